// Round 1
// baseline (1021.063 us; speedup 1.0000x reference)
//
#include <hip/hip_runtime.h>
#include <hip/hip_bf16.h>

#define NN 100000
#define EE 1600000
#define CH 64
#define ED 16
#define HID 32
#define NBKT 782     // ceil(NN/128); bucket = col >> 7 (128 nodes per bucket)
#define BCAP 2304    // bucket capacity: mean 2048, +5.6 sigma

__device__ __forceinline__ float sigm(float x) { return 1.0f / (1.0f + __expf(-x)); }

// K1: fused edge-MLP gate + coarse binning + deg accumulation.
// Block = 2048 edges, 512 threads. alpha staged in LDS between the two passes
// (no global alpha array). deg[col] += alpha via native global f32 atomic.
__global__ void __launch_bounds__(512) gate_bin_kernel(
    const float* __restrict__ ea,
    const float* __restrict__ W1, const float* __restrict__ b1,
    const float* __restrict__ W2, const float* __restrict__ b2,
    const int* __restrict__ ei,
    int* __restrict__ gcursor, float* __restrict__ deg,
    unsigned long long* __restrict__ binned)
{
    __shared__ int   hist[NBKT];
    __shared__ int   base[NBKT];
    __shared__ float sal[2048];
    __shared__ int   scol[2048];
    int t = threadIdx.x;
    for (int i = t; i < NBKT; i += 512) hist[i] = 0;
    __syncthreads();
    int e0 = blockIdx.x * 2048;
#pragma unroll 1
    for (int k = 0; k < 4; k++) {
        int idx = k * 512 + t;
        int e = e0 + idx;
        if (e < EE) {
            const float4* p = (const float4*)(ea + (size_t)e * ED);
            float4 q0 = p[0], q1 = p[1], q2 = p[2], q3 = p[3];
            float a[ED] = {q0.x, q0.y, q0.z, q0.w, q1.x, q1.y, q1.z, q1.w,
                           q2.x, q2.y, q2.z, q2.w, q3.x, q3.y, q3.z, q3.w};
            float acc = b2[0];
#pragma unroll
            for (int j = 0; j < HID; j++) {
                float hj = b1[j];
#pragma unroll
                for (int kk = 0; kk < ED; kk++) hj = fmaf(a[kk], W1[kk * HID + j], hj);
                hj *= sigm(hj);
                acc = fmaf(hj, W2[j], acc);
            }
            float alv = sigm(acc);
            int cv = ei[EE + e];
            sal[idx] = alv;
            scol[idx] = cv;
            atomicAdd(&hist[cv >> 7], 1);
            unsafeAtomicAdd(&deg[cv], alv);   // native global_atomic_add_f32
        }
    }
    __syncthreads();
    for (int i = t; i < NBKT; i += 512) {
        int c0 = hist[i];
        base[i] = c0 ? atomicAdd(&gcursor[i], c0) : 0;
        hist[i] = 0;
    }
    __syncthreads();
#pragma unroll 1
    for (int k = 0; k < 4; k++) {
        int idx = k * 512 + t;
        int e = e0 + idx;
        if (e < EE) {
            int row = ei[e];
            int cv = scol[idx];
            float alv = sal[idx];
            int bkt = cv >> 7;
            int slot = base[bkt] + atomicAdd(&hist[bkt], 1);
            if (slot < BCAP)
                binned[(size_t)bkt * BCAP + slot] =
                    ((unsigned long long)__float_as_uint(alv) << 32)
                    | (unsigned)(row | ((cv & 127) << 17));
        }
    }
}

// K2: dis = deg>0 ? rsqrt(deg) : 0
__global__ void __launch_bounds__(256) dis_kernel(
    const float* __restrict__ deg, float* __restrict__ dis)
{
    int i = blockIdx.x * 256 + threadIdx.x;
    if (i < NN) {
        float d = deg[i];
        dis[i] = (d > 0.0f) ? rsqrtf(d) : 0.0f;
    }
}

// K3: xwh = bf16( (x @ W) * dis[row] ).  dis folded here so the per-edge
// gather never needs dis[row]. 16 rows/block amortizes the 16 KB W load.
__global__ void __launch_bounds__(256) xw_kernel(
    const float* __restrict__ x, const float* __restrict__ W,
    const float* __restrict__ dis, __hip_bfloat16* __restrict__ xwh)
{
    __shared__ float sW[CH * CH];
    __shared__ float sx[16][CH];
    int t = threadIdx.x;
    for (int i = t; i < CH * CH; i += 256) sW[i] = W[i];
    for (int i = t; i < 16 * CH; i += 256)
        sx[i >> 6][i & 63] = x[(size_t)blockIdx.x * (16 * CH) + i];
    __syncthreads();
    int rr = t >> 6, cc = t & 63;
    float a0 = 0.f, a1 = 0.f, a2 = 0.f, a3 = 0.f;
#pragma unroll
    for (int k = 0; k < CH; k += 4) {
        float4 x0 = *(const float4*)&sx[rr][k];
        float4 x1 = *(const float4*)&sx[rr + 4][k];
        float4 x2 = *(const float4*)&sx[rr + 8][k];
        float4 x3 = *(const float4*)&sx[rr + 12][k];
        float w0 = sW[k * CH + cc],       w1 = sW[(k + 1) * CH + cc];
        float w2 = sW[(k + 2) * CH + cc], w3 = sW[(k + 3) * CH + cc];
        a0 = fmaf(x0.x, w0, a0); a0 = fmaf(x0.y, w1, a0); a0 = fmaf(x0.z, w2, a0); a0 = fmaf(x0.w, w3, a0);
        a1 = fmaf(x1.x, w0, a1); a1 = fmaf(x1.y, w1, a1); a1 = fmaf(x1.z, w2, a1); a1 = fmaf(x1.w, w3, a1);
        a2 = fmaf(x2.x, w0, a2); a2 = fmaf(x2.y, w1, a2); a2 = fmaf(x2.z, w2, a2); a2 = fmaf(x2.w, w3, a2);
        a3 = fmaf(x3.x, w0, a3); a3 = fmaf(x3.y, w1, a3); a3 = fmaf(x3.z, w2, a3); a3 = fmaf(x3.w, w3, a3);
    }
    int r0 = blockIdx.x * 16;
    xwh[(size_t)(r0 + rr) * CH + cc]      = __float2bfloat16(a0 * dis[r0 + rr]);
    xwh[(size_t)(r0 + rr + 4) * CH + cc]  = __float2bfloat16(a1 * dis[r0 + rr + 4]);
    xwh[(size_t)(r0 + rr + 8) * CH + cc]  = __float2bfloat16(a2 * dis[r0 + rr + 8]);
    xwh[(size_t)(r0 + rr + 12) * CH + cc] = __float2bfloat16(a3 * dis[r0 + rr + 12]);
}

// K4: per-bucket message accumulation directly into LDS acc[128][64]
// (one conflict-free ds_add_f32 per edge: lanes 0..63 hit distinct banks),
// then bias + LayerNorm + SiLU + residual in place. Replaces the entire
// bscan/fine_place/CSR/gather machinery.
__global__ void __launch_bounds__(512) accum_finalize_kernel(
    const unsigned long long* __restrict__ binned, const int* __restrict__ gcursor,
    const float* __restrict__ dis, const __hip_bfloat16* __restrict__ xwh,
    const float* __restrict__ x, const float* __restrict__ b,
    const float* __restrict__ gamma, const float* __restrict__ beta,
    float* __restrict__ out)
{
    __shared__ float acc[128][CH];   // 32 KB
    __shared__ float sdis[128];
    int t = threadIdx.x;
    int bkt = blockIdx.x;
    int size = gcursor[bkt];
    if (size > BCAP) size = BCAP;
    {
        float4* az = (float4*)&acc[0][0];
        float4 z4 = make_float4(0.f, 0.f, 0.f, 0.f);
        for (int i = t; i < 128 * CH / 4; i += 512) az[i] = z4;
    }
    if (t < 128) {
        int node = bkt * 128 + t;
        sdis[t] = (node < NN) ? dis[node] : 0.0f;
    }
    __syncthreads();
    const unsigned long long* bb = binned + (size_t)bkt * BCAP;
    int c = t & 63, wid = t >> 6;
    for (int i = wid * 4; i < size; i += 32) {
        if (size - i >= 4) {
            ulonglong2 p0 = *(const ulonglong2*)(bb + i);
            ulonglong2 p1 = *(const ulonglong2*)(bb + i + 2);
            unsigned lo0 = (unsigned)p0.x, lo1 = (unsigned)p0.y;
            unsigned lo2 = (unsigned)p1.x, lo3 = (unsigned)p1.y;
            int r0 = lo0 & 0x1FFFF, r1 = lo1 & 0x1FFFF;
            int r2 = lo2 & 0x1FFFF, r3 = lo3 & 0x1FFFF;
            float v0 = __bfloat162float(xwh[(size_t)r0 * CH + c]);
            float v1 = __bfloat162float(xwh[(size_t)r1 * CH + c]);
            float v2 = __bfloat162float(xwh[(size_t)r2 * CH + c]);
            float v3 = __bfloat162float(xwh[(size_t)r3 * CH + c]);
            int cl0 = (lo0 >> 17) & 127, cl1 = (lo1 >> 17) & 127;
            int cl2 = (lo2 >> 17) & 127, cl3 = (lo3 >> 17) & 127;
            float w0 = __uint_as_float((unsigned)(p0.x >> 32)) * sdis[cl0];
            float w1 = __uint_as_float((unsigned)(p0.y >> 32)) * sdis[cl1];
            float w2 = __uint_as_float((unsigned)(p1.x >> 32)) * sdis[cl2];
            float w3 = __uint_as_float((unsigned)(p1.y >> 32)) * sdis[cl3];
            unsafeAtomicAdd(&acc[cl0][c], v0 * w0);
            unsafeAtomicAdd(&acc[cl1][c], v1 * w1);
            unsafeAtomicAdd(&acc[cl2][c], v2 * w2);
            unsafeAtomicAdd(&acc[cl3][c], v3 * w3);
        } else {
            for (int k = i; k < size; k++) {
                unsigned long long p = bb[k];
                unsigned lo = (unsigned)p;
                int r = lo & 0x1FFFF;
                int cl = (lo >> 17) & 127;
                float w = __uint_as_float((unsigned)(p >> 32)) * sdis[cl];
                unsafeAtomicAdd(&acc[cl][c], __bfloat162float(xwh[(size_t)r * CH + c]) * w);
            }
        }
    }
    __syncthreads();
    float bc = b[c], gc = gamma[c], be = beta[c];
    for (int n = wid; n < 128; n += 8) {
        int node = bkt * 128 + n;
        if (node >= NN) break;
        float hv = acc[n][c] + bc;
        float ssum = hv;
#pragma unroll
        for (int off = 32; off; off >>= 1) ssum += __shfl_xor(ssum, off, 64);
        float mu = ssum * (1.0f / 64.0f);
        float d = hv - mu;
        float v2 = d * d;
#pragma unroll
        for (int off = 32; off; off >>= 1) v2 += __shfl_xor(v2, off, 64);
        float y = d * rsqrtf(v2 * (1.0f / 64.0f) + 1e-5f) * gc + be;
        y *= sigm(y);
        size_t idx = (size_t)node * CH + c;
        out[idx] = y + x[idx];
    }
}

extern "C" void kernel_launch(void* const* d_in, const int* in_sizes, int n_in,
                              void* d_out, int out_size, void* d_ws, size_t ws_size,
                              hipStream_t stream)
{
    const float* x     = (const float*)d_in[0];
    const int*   ei    = (const int*)d_in[1];
    const float* ea    = (const float*)d_in[2];
    const float* W     = (const float*)d_in[3];
    const float* b     = (const float*)d_in[4];
    const float* W1    = (const float*)d_in[5];
    const float* b1    = (const float*)d_in[6];
    const float* W2    = (const float*)d_in[7];
    const float* b2    = (const float*)d_in[8];
    const float* gamma = (const float*)d_in[9];
    const float* beta  = (const float*)d_in[10];
    float* out = (float*)d_out;

    // ws layout: binned u64[NBKT*BCAP] | xwh bf16[NN*CH] | deg f32[NN]
    //            | gcursor i32[NBKT] | dis f32[NN]
    unsigned long long* binned = (unsigned long long*)d_ws;
    __hip_bfloat16* xwh = (__hip_bfloat16*)(binned + (size_t)NBKT * BCAP);
    float* deg     = (float*)(xwh + (size_t)NN * CH);
    int*   gcursor = (int*)(deg + NN);
    float* dis     = (float*)(gcursor + NBKT);

    hipMemsetAsync(deg, 0, (NN + NBKT) * sizeof(float), stream);  // deg + gcursor

    gate_bin_kernel<<<(EE + 2047) / 2048, 512, 0, stream>>>(ea, W1, b1, W2, b2, ei,
                                                            gcursor, deg, binned);
    dis_kernel<<<(NN + 255) / 256, 256, 0, stream>>>(deg, dis);
    xw_kernel<<<NN / 16, 256, 0, stream>>>(x, W, dis, xwh);
    accum_finalize_kernel<<<NBKT, 512, 0, stream>>>(binned, gcursor, dis, xwh,
                                                    x, b, gamma, beta, out);
}

// Round 2
// 921.045 us; speedup vs baseline: 1.1086x; 1.1086x over previous
//
#include <hip/hip_runtime.h>
#include <hip/hip_bf16.h>

#define NN 100000
#define EE 1600000
#define CH 64
#define ED 16
#define HID 32
#define NBKT 1563    // ceil(NN/64); bucket = col >> 6 (64 nodes per bucket)
#define BCAP 1216    // bucket capacity: mean 1024, +6 sigma

__device__ __forceinline__ float sigm(float x) {
    return __builtin_amdgcn_rcpf(1.0f + __expf(-x));
}

// LDS f32 atomic add — relaxed, workgroup scope -> ds_add_f32
__device__ __forceinline__ void lds_fadd(float* p, float v) {
    __hip_atomic_fetch_add(p, v, __ATOMIC_RELAXED, __HIP_MEMORY_SCOPE_WORKGROUP);
}

// K1: fused edge-MLP gate + coarse binning + deg accumulation.
// Block = 4096 edges, 512 threads. alpha staged in LDS between the two passes.
__global__ void __launch_bounds__(512) gate_bin_kernel(
    const float* __restrict__ ea,
    const float* __restrict__ W1, const float* __restrict__ b1,
    const float* __restrict__ W2, const float* __restrict__ b2,
    const int* __restrict__ ei,
    int* __restrict__ gcursor, float* __restrict__ deg,
    unsigned long long* __restrict__ binned)
{
    __shared__ int   hist[NBKT];
    __shared__ int   base[NBKT];
    __shared__ float sal[4096];
    __shared__ int   scol[4096];
    int t = threadIdx.x;
    for (int i = t; i < NBKT; i += 512) hist[i] = 0;
    __syncthreads();
    int e0 = blockIdx.x * 4096;
#pragma unroll 1
    for (int k = 0; k < 8; k++) {
        int idx = k * 512 + t;
        int e = e0 + idx;
        if (e < EE) {
            const float4* p = (const float4*)(ea + (size_t)e * ED);
            float4 q0 = p[0], q1 = p[1], q2 = p[2], q3 = p[3];
            float a[ED] = {q0.x, q0.y, q0.z, q0.w, q1.x, q1.y, q1.z, q1.w,
                           q2.x, q2.y, q2.z, q2.w, q3.x, q3.y, q3.z, q3.w};
            float acc = b2[0];
#pragma unroll
            for (int j = 0; j < HID; j++) {
                float hj = b1[j];
#pragma unroll
                for (int kk = 0; kk < ED; kk++) hj = fmaf(a[kk], W1[kk * HID + j], hj);
                hj *= sigm(hj);
                acc = fmaf(hj, W2[j], acc);
            }
            float alv = sigm(acc);
            int cv = ei[EE + e];
            sal[idx] = alv;
            scol[idx] = cv;
            atomicAdd(&hist[cv >> 6], 1);
            unsafeAtomicAdd(&deg[cv], alv);   // native global_atomic_add_f32
        }
    }
    __syncthreads();
    for (int i = t; i < NBKT; i += 512) {
        int c0 = hist[i];
        base[i] = c0 ? atomicAdd(&gcursor[i], c0) : 0;
        hist[i] = 0;
    }
    __syncthreads();
#pragma unroll 1
    for (int k = 0; k < 8; k++) {
        int idx = k * 512 + t;
        int e = e0 + idx;
        if (e < EE) {
            int row = ei[e];
            int cv = scol[idx];
            float alv = sal[idx];
            int bkt = cv >> 6;
            int slot = base[bkt] + atomicAdd(&hist[bkt], 1);
            if (slot < BCAP)
                binned[(size_t)bkt * BCAP + slot] =
                    ((unsigned long long)__float_as_uint(alv) << 32)
                    | (unsigned)(row | ((cv & 63) << 17));
        }
    }
}

// K2: dis = deg>0 ? rsqrt(deg) : 0
__global__ void __launch_bounds__(256) dis_kernel(
    const float* __restrict__ deg, float* __restrict__ dis)
{
    int i = blockIdx.x * 256 + threadIdx.x;
    if (i < NN) {
        float d = deg[i];
        dis[i] = (d > 0.0f) ? rsqrtf(d) : 0.0f;
    }
}

// K3: xwh = bf16( (x @ W) * dis[row] ).  dis[row] folded here so the per-edge
// path never touches it. 16 rows/block amortizes the 16 KB W load.
__global__ void __launch_bounds__(256) xw_kernel(
    const float* __restrict__ x, const float* __restrict__ W,
    const float* __restrict__ dis, __hip_bfloat16* __restrict__ xwh)
{
    __shared__ float sW[CH * CH];
    __shared__ float sx[16][CH];
    int t = threadIdx.x;
    for (int i = t; i < CH * CH; i += 256) sW[i] = W[i];
    for (int i = t; i < 16 * CH; i += 256)
        sx[i >> 6][i & 63] = x[(size_t)blockIdx.x * (16 * CH) + i];
    __syncthreads();
    int rr = t >> 6, cc = t & 63;
    float a0 = 0.f, a1 = 0.f, a2 = 0.f, a3 = 0.f;
#pragma unroll
    for (int k = 0; k < CH; k += 4) {
        float4 x0 = *(const float4*)&sx[rr][k];
        float4 x1 = *(const float4*)&sx[rr + 4][k];
        float4 x2 = *(const float4*)&sx[rr + 8][k];
        float4 x3 = *(const float4*)&sx[rr + 12][k];
        float w0 = sW[k * CH + cc],       w1 = sW[(k + 1) * CH + cc];
        float w2 = sW[(k + 2) * CH + cc], w3 = sW[(k + 3) * CH + cc];
        a0 = fmaf(x0.x, w0, a0); a0 = fmaf(x0.y, w1, a0); a0 = fmaf(x0.z, w2, a0); a0 = fmaf(x0.w, w3, a0);
        a1 = fmaf(x1.x, w0, a1); a1 = fmaf(x1.y, w1, a1); a1 = fmaf(x1.z, w2, a1); a1 = fmaf(x1.w, w3, a1);
        a2 = fmaf(x2.x, w0, a2); a2 = fmaf(x2.y, w1, a2); a2 = fmaf(x2.z, w2, a2); a2 = fmaf(x2.w, w3, a2);
        a3 = fmaf(x3.x, w0, a3); a3 = fmaf(x3.y, w1, a3); a3 = fmaf(x3.z, w2, a3); a3 = fmaf(x3.w, w3, a3);
    }
    int r0 = blockIdx.x * 16;
    xwh[(size_t)(r0 + rr) * CH + cc]      = __float2bfloat16(a0 * dis[r0 + rr]);
    xwh[(size_t)(r0 + rr + 4) * CH + cc]  = __float2bfloat16(a1 * dis[r0 + rr + 4]);
    xwh[(size_t)(r0 + rr + 8) * CH + cc]  = __float2bfloat16(a2 * dis[r0 + rr + 8]);
    xwh[(size_t)(r0 + rr + 12) * CH + cc] = __float2bfloat16(a3 * dis[r0 + rr + 12]);
}

// K4: per-bucket (64 nodes) message accumulation into LDS acc[64][64] via
// ds_add_f32 (conflict-free: lanes 0..63 hit consecutive floats), then
// dis[col] + bias + LayerNorm + SiLU + residual. 256 thr, 16 KB LDS -> 8 blk/CU.
__global__ void __launch_bounds__(256) accum_finalize_kernel(
    const unsigned long long* __restrict__ binned, const int* __restrict__ gcursor,
    const float* __restrict__ dis, const __hip_bfloat16* __restrict__ xwh,
    const float* __restrict__ x, const float* __restrict__ b,
    const float* __restrict__ gamma, const float* __restrict__ beta,
    float* __restrict__ out)
{
    __shared__ float acc[64][CH];   // 16 KB
    int t = threadIdx.x;
    int bkt = blockIdx.x;
    int size = gcursor[bkt];
    if (size > BCAP) size = BCAP;
    {
        float4* az = (float4*)&acc[0][0];
        float4 z4 = make_float4(0.f, 0.f, 0.f, 0.f);
        for (int i = t; i < 64 * CH / 4; i += 256) az[i] = z4;
    }
    __syncthreads();
    const unsigned long long* bb = binned + (size_t)bkt * BCAP;
    int c = t & 63, wid = t >> 6;          // 4 waves
    int R = size & ~31;                    // full rounds of 32 (4 waves x 8)
    for (int ibase = wid * 8; ibase < R; ibase += 32) {
        ulonglong2 q0 = *(const ulonglong2*)(bb + ibase);
        ulonglong2 q1 = *(const ulonglong2*)(bb + ibase + 2);
        ulonglong2 q2 = *(const ulonglong2*)(bb + ibase + 4);
        ulonglong2 q3 = *(const ulonglong2*)(bb + ibase + 6);
        unsigned long long pp[8] = {q0.x, q0.y, q1.x, q1.y, q2.x, q2.y, q3.x, q3.y};
        int   rr_[8], cl_[8];
        float aa[8], vv[8];
#pragma unroll
        for (int j = 0; j < 8; j++) {
            unsigned lo = (unsigned)pp[j];
            rr_[j] = lo & 0x1FFFF;
            cl_[j] = (lo >> 17) & 63;
            aa[j]  = __uint_as_float((unsigned)(pp[j] >> 32));
        }
#pragma unroll
        for (int j = 0; j < 8; j++)
            vv[j] = __bfloat162float(xwh[rr_[j] * CH + c]);
#pragma unroll
        for (int j = 0; j < 8; j++)
            lds_fadd(&acc[cl_[j]][c], vv[j] * aa[j]);
    }
    for (int k = R + wid; k < size; k += 4) {
        unsigned long long p = bb[k];
        unsigned lo = (unsigned)p;
        int r = lo & 0x1FFFF;
        int cl = (lo >> 17) & 63;
        float a = __uint_as_float((unsigned)(p >> 32));
        lds_fadd(&acc[cl][c], __bfloat162float(xwh[r * CH + c]) * a);
    }
    __syncthreads();
    float bc = b[c], gc = gamma[c], be = beta[c];
    for (int n = wid; n < 64; n += 4) {
        int node = bkt * 64 + n;
        if (node >= NN) break;
        float hv = fmaf(acc[n][c], dis[node], bc);
        float ssum = hv;
#pragma unroll
        for (int off = 32; off; off >>= 1) ssum += __shfl_xor(ssum, off, 64);
        float mu = ssum * (1.0f / 64.0f);
        float d = hv - mu;
        float v2 = d * d;
#pragma unroll
        for (int off = 32; off; off >>= 1) v2 += __shfl_xor(v2, off, 64);
        float y = d * rsqrtf(v2 * (1.0f / 64.0f) + 1e-5f) * gc + be;
        y *= sigm(y);
        size_t idx = (size_t)node * CH + c;
        out[idx] = y + x[idx];
    }
}

extern "C" void kernel_launch(void* const* d_in, const int* in_sizes, int n_in,
                              void* d_out, int out_size, void* d_ws, size_t ws_size,
                              hipStream_t stream)
{
    const float* x     = (const float*)d_in[0];
    const int*   ei    = (const int*)d_in[1];
    const float* ea    = (const float*)d_in[2];
    const float* W     = (const float*)d_in[3];
    const float* b     = (const float*)d_in[4];
    const float* W1    = (const float*)d_in[5];
    const float* b1    = (const float*)d_in[6];
    const float* W2    = (const float*)d_in[7];
    const float* b2    = (const float*)d_in[8];
    const float* gamma = (const float*)d_in[9];
    const float* beta  = (const float*)d_in[10];
    float* out = (float*)d_out;

    // ws layout: binned u64[NBKT*BCAP] | xwh bf16[NN*CH] | deg f32[NN]
    //            | gcursor i32[NBKT] | dis f32[NN]
    unsigned long long* binned = (unsigned long long*)d_ws;
    __hip_bfloat16* xwh = (__hip_bfloat16*)(binned + (size_t)NBKT * BCAP);
    float* deg     = (float*)(xwh + (size_t)NN * CH);
    int*   gcursor = (int*)(deg + NN);
    float* dis     = (float*)(gcursor + NBKT);

    hipMemsetAsync(deg, 0, (NN + NBKT) * sizeof(float), stream);  // deg + gcursor

    gate_bin_kernel<<<(EE + 4095) / 4096, 512, 0, stream>>>(ea, W1, b1, W2, b2, ei,
                                                            gcursor, deg, binned);
    dis_kernel<<<(NN + 255) / 256, 256, 0, stream>>>(deg, dis);
    xw_kernel<<<NN / 16, 256, 0, stream>>>(x, W, dis, xwh);
    accum_finalize_kernel<<<NBKT, 256, 0, stream>>>(binned, gcursor, dis, xwh,
                                                    x, b, gamma, beta, out);
}

// Round 4
// 912.318 us; speedup vs baseline: 1.1192x; 1.0096x over previous
//
#include <hip/hip_runtime.h>
#include <hip/hip_bf16.h>

#define NN 100000
#define EE 1600000
#define CH 64
#define ED 16
#define HID 32
#define NBKT 1563    // ceil(NN/64); bucket = col >> 6 (64 nodes per bucket)
#define BCAP 1216    // bucket capacity: mean 1024, +6 sigma

__device__ __forceinline__ float sigm(float x) {
    return __builtin_amdgcn_rcpf(1.0f + __expf(-x));
}

// Hardware LDS f32 atomic add via inline asm (compiler FP atomics on LDS all
// lower to CAS loops here: 620-714us, R1/R2). Low 32 bits of a generic pointer
// to LDS == LDS byte offset (addrspacecast(3->0) is {aperture_hi, offset_lo}).
// CRITICAL: asm DS ops are invisible to SIInsertWaitcnts -- the caller MUST
// drain lgkmcnt manually before any barrier that publishes the results (R3
// failed exactly this way: in-flight ds_adds at s_barrier -> lost updates).
__device__ __forceinline__ void lds_fadd(float* p, float v) {
    asm volatile("ds_add_f32 %0, %1"
                 :: "v"((unsigned)(unsigned long long)p), "v"(v));
}

// K1: fused edge-MLP gate + coarse binning + deg accumulation.
// Block = 4096 edges, 512 threads. alpha staged in LDS between the two passes.
__global__ void __launch_bounds__(512) gate_bin_kernel(
    const float* __restrict__ ea,
    const float* __restrict__ W1, const float* __restrict__ b1,
    const float* __restrict__ W2, const float* __restrict__ b2,
    const int* __restrict__ ei,
    int* __restrict__ gcursor, float* __restrict__ deg,
    unsigned long long* __restrict__ binned)
{
    __shared__ int   hist[NBKT];
    __shared__ int   base[NBKT];
    __shared__ float sal[4096];
    __shared__ int   scol[4096];
    int t = threadIdx.x;
    for (int i = t; i < NBKT; i += 512) hist[i] = 0;
    __syncthreads();
    int e0 = blockIdx.x * 4096;
#pragma unroll 1
    for (int k = 0; k < 8; k++) {
        int idx = k * 512 + t;
        int e = e0 + idx;
        if (e < EE) {
            const float4* p = (const float4*)(ea + (size_t)e * ED);
            float4 q0 = p[0], q1 = p[1], q2 = p[2], q3 = p[3];
            float a[ED] = {q0.x, q0.y, q0.z, q0.w, q1.x, q1.y, q1.z, q1.w,
                           q2.x, q2.y, q2.z, q2.w, q3.x, q3.y, q3.z, q3.w};
            float acc = b2[0];
#pragma unroll
            for (int j = 0; j < HID; j++) {
                float hj = b1[j];
#pragma unroll
                for (int kk = 0; kk < ED; kk++) hj = fmaf(a[kk], W1[kk * HID + j], hj);
                hj *= sigm(hj);
                acc = fmaf(hj, W2[j], acc);
            }
            float alv = sigm(acc);
            int cv = ei[EE + e];
            sal[idx] = alv;
            scol[idx] = cv;
            atomicAdd(&hist[cv >> 6], 1);            // int LDS atomic: native ds_add_u32
            unsafeAtomicAdd(&deg[cv], alv);          // global f32 atomic: native
        }
    }
    __syncthreads();
    for (int i = t; i < NBKT; i += 512) {
        int c0 = hist[i];
        base[i] = c0 ? atomicAdd(&gcursor[i], c0) : 0;
        hist[i] = 0;
    }
    __syncthreads();
#pragma unroll 1
    for (int k = 0; k < 8; k++) {
        int idx = k * 512 + t;
        int e = e0 + idx;
        if (e < EE) {
            int row = ei[e];
            int cv = scol[idx];
            float alv = sal[idx];
            int bkt = cv >> 6;
            int slot = base[bkt] + atomicAdd(&hist[bkt], 1);
            if (slot < BCAP)
                binned[(size_t)bkt * BCAP + slot] =
                    ((unsigned long long)__float_as_uint(alv) << 32)
                    | (unsigned)(row | ((cv & 63) << 17));
        }
    }
}

// K2: dis = deg>0 ? rsqrt(deg) : 0
__global__ void __launch_bounds__(256) dis_kernel(
    const float* __restrict__ deg, float* __restrict__ dis)
{
    int i = blockIdx.x * 256 + threadIdx.x;
    if (i < NN) {
        float d = deg[i];
        dis[i] = (d > 0.0f) ? rsqrtf(d) : 0.0f;
    }
}

// K3: xwh = bf16( (x @ W) * dis[row] ). 32 rows/block halves W re-read (50 MB).
__global__ void __launch_bounds__(256) xw_kernel(
    const float* __restrict__ x, const float* __restrict__ W,
    const float* __restrict__ dis, __hip_bfloat16* __restrict__ xwh)
{
    __shared__ float sW[CH * CH];   // 16 KB
    __shared__ float sx[32][CH];    // 8 KB
    int t = threadIdx.x;
    for (int i = t; i < CH * CH; i += 256) sW[i] = W[i];
    for (int i = t; i < 32 * CH; i += 256)
        sx[i >> 6][i & 63] = x[(size_t)blockIdx.x * (32 * CH) + i];
    __syncthreads();
    int rr = t >> 6, cc = t & 63;
    float a[8] = {0.f, 0.f, 0.f, 0.f, 0.f, 0.f, 0.f, 0.f};
    for (int k = 0; k < CH; k += 4) {
        float w0 = sW[k * CH + cc],       w1 = sW[(k + 1) * CH + cc];
        float w2 = sW[(k + 2) * CH + cc], w3 = sW[(k + 3) * CH + cc];
#pragma unroll
        for (int j = 0; j < 8; j++) {
            float4 xv = *(const float4*)&sx[rr + 4 * j][k];
            a[j] = fmaf(xv.x, w0, a[j]);
            a[j] = fmaf(xv.y, w1, a[j]);
            a[j] = fmaf(xv.z, w2, a[j]);
            a[j] = fmaf(xv.w, w3, a[j]);
        }
    }
    int r0 = blockIdx.x * 32;
#pragma unroll
    for (int j = 0; j < 8; j++) {
        int r = r0 + rr + 4 * j;
        xwh[(size_t)r * CH + cc] = __float2bfloat16(a[j] * dis[r]);
    }
}

// K4: per-bucket (64 nodes) message accumulation into LDS acc[64][64] via
// native ds_add_f32 (conflict-free: lanes hit consecutive floats), then
// dis[col] + bias + LayerNorm + SiLU + residual. 256 thr, 16 KB LDS.
__global__ void __launch_bounds__(256) accum_finalize_kernel(
    const unsigned long long* __restrict__ binned, const int* __restrict__ gcursor,
    const float* __restrict__ dis, const __hip_bfloat16* __restrict__ xwh,
    const float* __restrict__ x, const float* __restrict__ b,
    const float* __restrict__ gamma, const float* __restrict__ beta,
    float* __restrict__ out)
{
    __shared__ float acc[64][CH];   // 16 KB
    int t = threadIdx.x;
    int bkt = blockIdx.x;
    int size = gcursor[bkt];
    if (size > BCAP) size = BCAP;
    {
        float4* az = (float4*)&acc[0][0];
        float4 z4 = make_float4(0.f, 0.f, 0.f, 0.f);
        for (int i = t; i < 64 * CH / 4; i += 256) az[i] = z4;
    }
    __syncthreads();
    const unsigned long long* bb = binned + (size_t)bkt * BCAP;
    int c = t & 63, wid = t >> 6;          // 4 waves
    int R = size & ~31;                    // full rounds of 32 (4 waves x 8)
    for (int ibase = wid * 8; ibase < R; ibase += 32) {
        ulonglong2 q0 = *(const ulonglong2*)(bb + ibase);
        ulonglong2 q1 = *(const ulonglong2*)(bb + ibase + 2);
        ulonglong2 q2 = *(const ulonglong2*)(bb + ibase + 4);
        ulonglong2 q3 = *(const ulonglong2*)(bb + ibase + 6);
        unsigned long long pp[8] = {q0.x, q0.y, q1.x, q1.y, q2.x, q2.y, q3.x, q3.y};
        int   rr_[8], cl_[8];
        float aa[8], vv[8];
#pragma unroll
        for (int j = 0; j < 8; j++) {
            unsigned lo = (unsigned)pp[j];
            rr_[j] = lo & 0x1FFFF;
            cl_[j] = (lo >> 17) & 63;
            aa[j]  = __uint_as_float((unsigned)(pp[j] >> 32));
        }
#pragma unroll
        for (int j = 0; j < 8; j++)
            vv[j] = __bfloat162float(xwh[rr_[j] * CH + c]);
#pragma unroll
        for (int j = 0; j < 8; j++)
            lds_fadd(&acc[cl_[j]][c], vv[j] * aa[j]);
    }
    for (int k = R + wid; k < size; k += 4) {
        unsigned long long p = bb[k];
        unsigned lo = (unsigned)p;
        int r = lo & 0x1FFFF;
        int cl = (lo >> 17) & 63;
        float a = __uint_as_float((unsigned)(p >> 32));
        lds_fadd(&acc[cl][c], __bfloat162float(xwh[r * CH + c]) * a);
    }
    // Drain this wave's asm-issued ds_adds BEFORE signaling the barrier:
    // SIInsertWaitcnts doesn't track inline-asm DS ops, so the barrier's own
    // waitcnt won't cover them (R3's lost-update race). The "memory" clobber
    // also stops GVN forwarding the zero-init stores into the reads below.
    asm volatile("s_waitcnt lgkmcnt(0)" ::: "memory");
    __syncthreads();
    float bc = b[c], gc = gamma[c], be = beta[c];
    for (int n = wid; n < 64; n += 4) {
        int node = bkt * 64 + n;
        if (node >= NN) break;
        float hv = fmaf(acc[n][c], dis[node], bc);
        float ssum = hv;
#pragma unroll
        for (int off = 32; off; off >>= 1) ssum += __shfl_xor(ssum, off, 64);
        float mu = ssum * (1.0f / 64.0f);
        float d = hv - mu;
        float v2 = d * d;
#pragma unroll
        for (int off = 32; off; off >>= 1) v2 += __shfl_xor(v2, off, 64);
        float y = d * rsqrtf(v2 * (1.0f / 64.0f) + 1e-5f) * gc + be;
        y *= sigm(y);
        size_t idx = (size_t)node * CH + c;
        out[idx] = y + x[idx];
    }
}

extern "C" void kernel_launch(void* const* d_in, const int* in_sizes, int n_in,
                              void* d_out, int out_size, void* d_ws, size_t ws_size,
                              hipStream_t stream)
{
    const float* x     = (const float*)d_in[0];
    const int*   ei    = (const int*)d_in[1];
    const float* ea    = (const float*)d_in[2];
    const float* W     = (const float*)d_in[3];
    const float* b     = (const float*)d_in[4];
    const float* W1    = (const float*)d_in[5];
    const float* b1    = (const float*)d_in[6];
    const float* W2    = (const float*)d_in[7];
    const float* b2    = (const float*)d_in[8];
    const float* gamma = (const float*)d_in[9];
    const float* beta  = (const float*)d_in[10];
    float* out = (float*)d_out;

    // ws layout: binned u64[NBKT*BCAP] | xwh bf16[NN*CH] | deg f32[NN]
    //            | gcursor i32[NBKT] | dis f32[NN]
    unsigned long long* binned = (unsigned long long*)d_ws;
    __hip_bfloat16* xwh = (__hip_bfloat16*)(binned + (size_t)NBKT * BCAP);
    float* deg     = (float*)(xwh + (size_t)NN * CH);
    int*   gcursor = (int*)(deg + NN);
    float* dis     = (float*)(gcursor + NBKT);

    hipMemsetAsync(deg, 0, (NN + NBKT) * sizeof(float), stream);  // deg + gcursor

    gate_bin_kernel<<<(EE + 4095) / 4096, 512, 0, stream>>>(ea, W1, b1, W2, b2, ei,
                                                            gcursor, deg, binned);
    dis_kernel<<<(NN + 255) / 256, 256, 0, stream>>>(deg, dis);
    xw_kernel<<<NN / 32, 256, 0, stream>>>(x, W, dis, xwh);
    accum_finalize_kernel<<<NBKT, 256, 0, stream>>>(binned, gcursor, dis, xwh,
                                                    x, b, gamma, beta, out);
}

// Round 5
// 347.509 us; speedup vs baseline: 2.9382x; 2.6253x over previous
//
#include <hip/hip_runtime.h>
#include <hip/hip_bf16.h>

#define NN 100000
#define EE 1600000
#define CH 64
#define ED 16
#define HID 32
#define NBKT 1563    // ceil(NN/64); bucket = col >> 6 (64 nodes per bucket)
#define BCAP 1216    // bucket capacity: mean 1024, +6 sigma

__device__ __forceinline__ float sigm(float x) {
    return __builtin_amdgcn_rcpf(1.0f + __expf(-x));
}

// Hardware LDS f32 atomic add via inline asm (compiler FP atomics on LDS lower
// to CAS loops: R1/R2). asm DS ops are invisible to SIInsertWaitcnts -- caller
// MUST drain lgkmcnt before any barrier publishing the results (R3 lesson).
__device__ __forceinline__ void lds_fadd(float* p, float v) {
    asm volatile("ds_add_f32 %0, %1"
                 :: "v"((unsigned)(unsigned long long)p), "v"(v));
}

// K1: fused edge-MLP gate + coarse binning. Block = 4096 edges, 512 threads.
// alpha staged in LDS between the two passes. (deg atomics removed: per-node
// alpha sums now computed in place_kernel's LDS.)
__global__ void __launch_bounds__(512) gate_bin_kernel(
    const float* __restrict__ ea,
    const float* __restrict__ W1, const float* __restrict__ b1,
    const float* __restrict__ W2, const float* __restrict__ b2,
    const int* __restrict__ ei,
    int* __restrict__ gcursor, unsigned long long* __restrict__ binned)
{
    __shared__ int   hist[NBKT];
    __shared__ int   base[NBKT];
    __shared__ float sal[4096];
    __shared__ int   scol[4096];
    int t = threadIdx.x;
    for (int i = t; i < NBKT; i += 512) hist[i] = 0;
    __syncthreads();
    int e0 = blockIdx.x * 4096;
#pragma unroll 1
    for (int k = 0; k < 8; k++) {
        int idx = k * 512 + t;
        int e = e0 + idx;
        if (e < EE) {
            const float4* p = (const float4*)(ea + (size_t)e * ED);
            float4 q0 = p[0], q1 = p[1], q2 = p[2], q3 = p[3];
            float a[ED] = {q0.x, q0.y, q0.z, q0.w, q1.x, q1.y, q1.z, q1.w,
                           q2.x, q2.y, q2.z, q2.w, q3.x, q3.y, q3.z, q3.w};
            float acc = b2[0];
#pragma unroll
            for (int j = 0; j < HID; j++) {
                float hj = b1[j];
#pragma unroll
                for (int kk = 0; kk < ED; kk++) hj = fmaf(a[kk], W1[kk * HID + j], hj);
                hj *= sigm(hj);
                acc = fmaf(hj, W2[j], acc);
            }
            float alv = sigm(acc);
            int cv = ei[EE + e];
            sal[idx] = alv;
            scol[idx] = cv;
            atomicAdd(&hist[cv >> 6], 1);            // native ds_add_u32
        }
    }
    __syncthreads();
    for (int i = t; i < NBKT; i += 512) {
        int c0 = hist[i];
        base[i] = c0 ? atomicAdd(&gcursor[i], c0) : 0;
        hist[i] = 0;
    }
    __syncthreads();
#pragma unroll 1
    for (int k = 0; k < 8; k++) {
        int idx = k * 512 + t;
        int e = e0 + idx;
        if (e < EE) {
            int row = ei[e];
            int cv = scol[idx];
            float alv = sal[idx];
            int bkt = cv >> 6;
            int slot = base[bkt] + atomicAdd(&hist[bkt], 1);
            if (slot < BCAP)
                binned[(size_t)bkt * BCAP + slot] =
                    ((unsigned long long)__float_as_uint(alv) << 32)
                    | (unsigned)(row | ((cv & 63) << 17));
        }
    }
}

// K2: per-bucket node-sort into CSR (integer-only ranking; the FP CAS poison
// of the old fine_place is gone). Also computes per-node alpha-sum -> dis,
// and nrange[node] = {start,end} into the bucket-padded csr.
__global__ void __launch_bounds__(256) place_kernel(
    const unsigned long long* __restrict__ binned, const int* __restrict__ gcursor,
    int2* __restrict__ nrange, float* __restrict__ dis, float2* __restrict__ csr)
{
    __shared__ int   cnt[64];
    __shared__ float nsum[64];
    __shared__ int   rk[64];
    __shared__ int   start[64];
    int t = threadIdx.x;
    int bkt = blockIdx.x;
    int size = gcursor[bkt];
    if (size > BCAP) size = BCAP;
    if (t < 64) { cnt[t] = 0; nsum[t] = 0.0f; rk[t] = 0; }
    __syncthreads();
    const unsigned long long* bb = binned + (size_t)bkt * BCAP;
    for (int i = t; i < size; i += 256) {
        unsigned long long p = bb[i];
        unsigned lo = (unsigned)p;
        int cl = (lo >> 17) & 63;
        atomicAdd(&cnt[cl], 1);                       // native ds_add_u32
        lds_fadd(&nsum[cl], __uint_as_float((unsigned)(p >> 32)));
    }
    // drain asm ds_adds before the barrier publishes nsum (R3 lesson)
    asm volatile("s_waitcnt lgkmcnt(0)" ::: "memory");
    __syncthreads();
    if (t < 64) {                                     // wave 0: 64-wide scan
        int orig = cnt[t];
        int v = orig;
#pragma unroll
        for (int off = 1; off < 64; off <<= 1) {
            int u = __shfl_up(v, off, 64);
            if (t >= off) v += u;
        }
        int excl = v - orig;
        int s = bkt * BCAP + excl;
        start[t] = s;
        int node = bkt * 64 + t;
        if (node < NN) {
            nrange[node] = make_int2(s, s + orig);
            float d = nsum[t];
            dis[node] = (d > 0.0f) ? rsqrtf(d) : 0.0f;
        }
    }
    __syncthreads();
    for (int i = t; i < size; i += 256) {
        unsigned long long p = bb[i];
        unsigned lo = (unsigned)p;
        int cl = (lo >> 17) & 63;
        int row = lo & 0x1FFFF;
        int r = atomicAdd(&rk[cl], 1);                // native ds_add_rtn_u32
        csr[start[cl] + r] =
            make_float2(__int_as_float(row), __uint_as_float((unsigned)(p >> 32)));
    }
}

// K3: xwh = bf16( (x @ W) * dis[row] ). 32 rows/block; runs after place_kernel
// (needs dis). Folding dis[row] here removes the per-edge dis gather entirely.
__global__ void __launch_bounds__(256) xw_kernel(
    const float* __restrict__ x, const float* __restrict__ W,
    const float* __restrict__ dis, __hip_bfloat16* __restrict__ xwh)
{
    __shared__ float sW[CH * CH];   // 16 KB
    __shared__ float sx[32][CH];    // 8 KB
    int t = threadIdx.x;
    for (int i = t; i < CH * CH; i += 256) sW[i] = W[i];
    for (int i = t; i < 32 * CH; i += 256)
        sx[i >> 6][i & 63] = x[(size_t)blockIdx.x * (32 * CH) + i];
    __syncthreads();
    int rr = t >> 6, cc = t & 63;
    float a[8] = {0.f, 0.f, 0.f, 0.f, 0.f, 0.f, 0.f, 0.f};
    for (int k = 0; k < CH; k += 4) {
        float w0 = sW[k * CH + cc],       w1 = sW[(k + 1) * CH + cc];
        float w2 = sW[(k + 2) * CH + cc], w3 = sW[(k + 3) * CH + cc];
#pragma unroll
        for (int j = 0; j < 8; j++) {
            float4 xv = *(const float4*)&sx[rr + 4 * j][k];
            a[j] = fmaf(xv.x, w0, a[j]);
            a[j] = fmaf(xv.y, w1, a[j]);
            a[j] = fmaf(xv.z, w2, a[j]);
            a[j] = fmaf(xv.w, w3, a[j]);
        }
    }
    int r0 = blockIdx.x * 32;
#pragma unroll
    for (int j = 0; j < 8; j++) {
        int r = r0 + rr + 4 * j;
        xwh[(size_t)r * CH + cc] = __float2bfloat16(a[j] * dis[r]);
    }
}

// K4: R0's harness-proven gather structure (77us): one wave per node, lane =
// channel, REGISTER accumulation over the node's contiguous CSR slice, 4-edge
// ILP with scalar float4 records, then LN + SiLU + residual. No LDS, no
// barriers. (vs R0: per-edge dis[r] load is gone -- folded into xwh.)
__global__ void __launch_bounds__(256) gather_finalize_kernel(
    const float2* __restrict__ csr, const int2* __restrict__ nrange,
    const float* __restrict__ dis, const __hip_bfloat16* __restrict__ xwh,
    const float* __restrict__ x, const float* __restrict__ b,
    const float* __restrict__ gamma, const float* __restrict__ beta,
    float* __restrict__ out)
{
    int t = threadIdx.x;
    int node = blockIdx.x * 4 + (t >> 6);
    int c = t & 63;
    int2 rg = nrange[node];
    int s = rg.x, en = rg.y;
    float acc = 0.0f;
    int i = s;
    if ((i & 1) && i < en) {
        float2 p = csr[i++];
        int r = __float_as_int(p.x);
        acc = fmaf(__bfloat162float(xwh[(size_t)r * CH + c]), p.y, acc);
    }
    for (; i + 3 < en; i += 4) {
        float4 q0 = *(const float4*)(csr + i);
        float4 q1 = *(const float4*)(csr + i + 2);
        int r0 = __float_as_int(q0.x), r1 = __float_as_int(q0.z);
        int r2 = __float_as_int(q1.x), r3 = __float_as_int(q1.z);
        acc = fmaf(__bfloat162float(xwh[(size_t)r0 * CH + c]), q0.y, acc);
        acc = fmaf(__bfloat162float(xwh[(size_t)r1 * CH + c]), q0.w, acc);
        acc = fmaf(__bfloat162float(xwh[(size_t)r2 * CH + c]), q1.y, acc);
        acc = fmaf(__bfloat162float(xwh[(size_t)r3 * CH + c]), q1.w, acc);
    }
    if (i + 1 < en) {
        float4 q0 = *(const float4*)(csr + i);
        int r0 = __float_as_int(q0.x), r1 = __float_as_int(q0.z);
        acc = fmaf(__bfloat162float(xwh[(size_t)r0 * CH + c]), q0.y, acc);
        acc = fmaf(__bfloat162float(xwh[(size_t)r1 * CH + c]), q0.w, acc);
        i += 2;
    }
    if (i < en) {
        float2 p = csr[i];
        int r = __float_as_int(p.x);
        acc = fmaf(__bfloat162float(xwh[(size_t)r * CH + c]), p.y, acc);
    }
    float hv = fmaf(acc, dis[node], b[c]);
    float ssum = hv;
#pragma unroll
    for (int off = 32; off; off >>= 1) ssum += __shfl_xor(ssum, off, 64);
    float mu = ssum * (1.0f / 64.0f);
    float d = hv - mu;
    float v2 = d * d;
#pragma unroll
    for (int off = 32; off; off >>= 1) v2 += __shfl_xor(v2, off, 64);
    float y = d * rsqrtf(v2 * (1.0f / 64.0f) + 1e-5f) * gamma[c] + beta[c];
    y *= sigm(y);
    size_t idx = (size_t)node * CH + c;
    out[idx] = y + x[idx];
}

extern "C" void kernel_launch(void* const* d_in, const int* in_sizes, int n_in,
                              void* d_out, int out_size, void* d_ws, size_t ws_size,
                              hipStream_t stream)
{
    const float* x     = (const float*)d_in[0];
    const int*   ei    = (const int*)d_in[1];
    const float* ea    = (const float*)d_in[2];
    const float* W     = (const float*)d_in[3];
    const float* b     = (const float*)d_in[4];
    const float* W1    = (const float*)d_in[5];
    const float* b1    = (const float*)d_in[6];
    const float* W2    = (const float*)d_in[7];
    const float* b2    = (const float*)d_in[8];
    const float* gamma = (const float*)d_in[9];
    const float* beta  = (const float*)d_in[10];
    float* out = (float*)d_out;

    // ws layout: binned u64[NBKT*BCAP] | csr f2[NBKT*BCAP] | xwh bf16[NN*CH]
    //            | nrange int2[NN] | dis f32[NN] | gcursor i32[NBKT]
    unsigned long long* binned = (unsigned long long*)d_ws;
    float2* csr    = (float2*)(binned + (size_t)NBKT * BCAP);
    __hip_bfloat16* xwh = (__hip_bfloat16*)(csr + (size_t)NBKT * BCAP);
    int2*  nrange  = (int2*)(xwh + (size_t)NN * CH);
    float* dis     = (float*)(nrange + NN);
    int*   gcursor = (int*)(dis + NN);

    hipMemsetAsync(gcursor, 0, NBKT * sizeof(int), stream);

    gate_bin_kernel<<<(EE + 4095) / 4096, 512, 0, stream>>>(ea, W1, b1, W2, b2, ei,
                                                            gcursor, binned);
    place_kernel<<<NBKT, 256, 0, stream>>>(binned, gcursor, nrange, dis, csr);
    xw_kernel<<<NN / 32, 256, 0, stream>>>(x, W, dis, xwh);
    gather_finalize_kernel<<<NN / 4, 256, 0, stream>>>(csr, nrange, dis, xwh,
                                                       x, b, gamma, beta, out);
}